// Round 1
// baseline (842.068 us; speedup 1.0000x reference)
//
#include <hip/hip_runtime.h>

#define IN_C 512
#define HEAD_C 64
#define NHEAD 8
#define TIME_C 256
#define EXPAND_C 2048
#define NB 4
#define NN 2048
#define QKV_DIM 5120   /* 64*8*2 + 512*8 */
#define ROWS (NB*NN)   /* 8192 */
#define MERGE_K (NHEAD*IN_C) /* 4096 */
#define LN2_C (IN_C+TIME_C)  /* 768 */

typedef __bf16 bf16x8 __attribute__((ext_vector_type(8)));
typedef float f32x4 __attribute__((ext_vector_type(4)));

__device__ __forceinline__ unsigned short f2bf(float f){
  unsigned int u = __builtin_bit_cast(unsigned int, f);
  u += 0x7fffu + ((u >> 16) & 1u);
  return (unsigned short)(u >> 16);
}

// ---------------- weight cast + transpose: W[K][N] f32 -> Wt[N][K] bf16 ----------------
__global__ __launch_bounds__(256) void k_transpose_w(const float* __restrict__ W,
                                                     unsigned short* __restrict__ Wt,
                                                     int K, int N){
  __shared__ unsigned short tile[64*72];
  int t = threadIdx.x;
  int kb = blockIdx.y<<6, nb = blockIdx.x<<6;
  {
    int kr = t>>2, nc = (t&3)<<4;
    const float* src = W + (size_t)(kb+kr)*N + nb + nc;
    alignas(16) unsigned short tmp[16];
    #pragma unroll
    for (int j=0;j<16;j+=4){
      float4 v = *(const float4*)(src + j);
      tmp[j+0]=f2bf(v.x); tmp[j+1]=f2bf(v.y); tmp[j+2]=f2bf(v.z); tmp[j+3]=f2bf(v.w);
    }
    *(bf16x8*)&tile[kr*72 + nc]     = *(bf16x8*)&tmp[0];
    *(bf16x8*)&tile[kr*72 + nc + 8] = *(bf16x8*)&tmp[8];
  }
  __syncthreads();
  {
    int nr = t>>2, kc = (t&3)<<4;
    alignas(16) unsigned short ov[16];
    #pragma unroll
    for (int j=0;j<16;j++) ov[j] = tile[(kc+j)*72 + nr];
    unsigned short* dst = Wt + (size_t)(nb+nr)*K + kb + kc;
    *(bf16x8*)dst     = *(bf16x8*)&ov[0];
    *(bf16x8*)(dst+8) = *(bf16x8*)&ov[8];
  }
}

// ---------------- V transpose: qkv[.,1024+h*512+d] -> Vt[bh][d][n] bf16 ----------------
__global__ __launch_bounds__(256) void k_transpose_v(const unsigned short* __restrict__ qkv,
                                                     unsigned short* __restrict__ Vt){
  __shared__ unsigned short tile[64*72];
  int j = blockIdx.x;              // bh(32) x db(8) x nb(32)
  int nbk = j&31, db=(j>>5)&7, bh=j>>8;
  int b = bh>>3, h = bh&7;
  int t = threadIdx.x;
  {
    int nr = t>>2, dc = (t&3)<<4;
    const unsigned short* src = qkv + (size_t)(b*NN + nbk*64 + nr)*QKV_DIM + 2*IN_C + h*IN_C + db*64 + dc;
    *(bf16x8*)&tile[nr*72 + dc]     = *(const bf16x8*)src;
    *(bf16x8*)&tile[nr*72 + dc + 8] = *(const bf16x8*)(src+8);
  }
  __syncthreads();
  {
    int dr = t>>2, nc = (t&3)<<4;
    alignas(16) unsigned short ov[16];
    #pragma unroll
    for (int i=0;i<16;i++) ov[i] = tile[(nc+i)*72 + dr];
    unsigned short* dst = Vt + ((size_t)bh*IN_C + db*64 + dr)*NN + nbk*64 + nc;
    *(bf16x8*)dst     = *(bf16x8*)&ov[0];
    *(bf16x8*)(dst+8) = *(bf16x8*)&ov[8];
  }
}

// ---------------- LN1: x[8192][512] f32 -> bf16 ----------------
__global__ __launch_bounds__(256) void k_ln1(const float* __restrict__ x,
                                             const float* __restrict__ g,
                                             const float* __restrict__ bta,
                                             unsigned short* __restrict__ out){
  int row = (blockIdx.x<<2) + (threadIdx.x>>6);
  int l = threadIdx.x&63;
  const float* px = x + (size_t)row*IN_C + l*8;
  alignas(16) float v[8];
  *(float4*)&v[0] = *(const float4*)px;
  *(float4*)&v[4] = *(const float4*)(px+4);
  float s=0.f, sq=0.f;
  #pragma unroll
  for (int j=0;j<8;j++){ s+=v[j]; sq+=v[j]*v[j]; }
  #pragma unroll
  for (int d=32; d>0; d>>=1){ s += __shfl_xor(s,d); sq += __shfl_xor(sq,d); }
  float mu = s*(1.f/IN_C);
  float var = sq*(1.f/IN_C) - mu*mu;
  float rstd = rsqrtf(var + 1e-5f);
  alignas(16) unsigned short o[8];
  #pragma unroll
  for (int j=0;j<8;j++){
    int c = l*8+j;
    o[j] = f2bf((v[j]-mu)*rstd*g[c] + bta[c]);
  }
  *(bf16x8*)(out + (size_t)row*IN_C + l*8) = *(bf16x8*)o;
}

// ---------------- time MLP: tt[b][j] = t[b] @ W + b ----------------
__global__ __launch_bounds__(256) void k_time(const float* __restrict__ t,
                                              const float* __restrict__ W,
                                              const float* __restrict__ bias,
                                              float* __restrict__ tt){
  int b = blockIdx.x, j = threadIdx.x;
  float acc = bias[j];
  const float* tr = t + b*TIME_C;
  #pragma unroll 4
  for (int c=0;c<TIME_C;c++) acc = fmaf(tr[c], W[c*TIME_C + j], acc);
  tt[b*TIME_C + j] = acc;
}

// ---------------- LN2 over concat(x2[512], tt[256]) -> bf16[8192][768] ----------------
__global__ __launch_bounds__(256) void k_ln2(const float* __restrict__ x2,
                                             const float* __restrict__ tt,
                                             const float* __restrict__ g,
                                             const float* __restrict__ bta,
                                             unsigned short* __restrict__ out){
  int row = (blockIdx.x<<2) + (threadIdx.x>>6);
  int l = threadIdx.x&63;
  int bi = row>>11;
  float v[12];
  int c0 = l*12;
  #pragma unroll
  for (int j=0;j<12;j++){
    int c = c0+j;
    v[j] = (c < IN_C) ? x2[(size_t)row*IN_C + c] : tt[bi*TIME_C + c - IN_C];
  }
  float s=0.f, sq=0.f;
  #pragma unroll
  for (int j=0;j<12;j++){ s+=v[j]; sq+=v[j]*v[j]; }
  #pragma unroll
  for (int d=32; d>0; d>>=1){ s += __shfl_xor(s,d); sq += __shfl_xor(sq,d); }
  float mu = s*(1.f/LN2_C);
  float var = sq*(1.f/LN2_C) - mu*mu;
  float rstd = rsqrtf(var + 1e-5f);
  #pragma unroll
  for (int j=0;j<12;j++){
    int c = c0+j;
    out[(size_t)row*LN2_C + c] = f2bf((v[j]-mu)*rstd*g[c] + bta[c]);
  }
}

// ---------------- GEMM: C[M][N] = A[M][K](bf16) @ Bt[N][K]^T(bf16) + bias (+res) ----------------
// EPI: 0 = bf16 out; 1 = f32 out + residual; 2 = bf16 out + exact gelu
template<int EPI>
__global__ __launch_bounds__(256) void k_gemm(const unsigned short* __restrict__ A, int lda,
                                              const unsigned short* __restrict__ Bt, int ldb,
                                              const float* __restrict__ bias,
                                              const float* __restrict__ res, int ldres,
                                              void* __restrict__ Cp, int ldc, int K){
  __shared__ unsigned short sA[128*40];   // [128 rows][32 k, pad to 40]
  __shared__ unsigned short sB[128*40];
  int t = threadIdx.x;
  int l = t&63, w = t>>6;
  int m0 = blockIdx.y<<7, n0 = blockIdx.x<<7;
  int wr = (w>>1)<<6, wc = (w&1)<<6;
  int lm = l&15, kq = (l>>4)<<3;
  f32x4 acc[4][4] = {};
  int sr = t>>2, sc = (t&3)<<3;
  const unsigned short* pA = A + (size_t)(m0+sr)*lda + sc;
  const unsigned short* pB = Bt + (size_t)(n0+sr)*ldb + sc;
  int soff = sr*40 + sc;
  for (int k0=0; k0<K; k0+=32){
    bf16x8 a0 = *(const bf16x8*)pA;
    bf16x8 a1 = *(const bf16x8*)(pA + (size_t)64*lda);
    bf16x8 b0 = *(const bf16x8*)pB;
    bf16x8 b1 = *(const bf16x8*)(pB + (size_t)64*ldb);
    pA += 32; pB += 32;
    __syncthreads();
    *(bf16x8*)&sA[soff]         = a0;
    *(bf16x8*)&sA[soff + 64*40] = a1;
    *(bf16x8*)&sB[soff]         = b0;
    *(bf16x8*)&sB[soff + 64*40] = b1;
    __syncthreads();
    bf16x8 af[4], bfv[4];
    #pragma unroll
    for (int i=0;i<4;i++){
      af[i]  = *(const bf16x8*)&sA[(wr + i*16 + lm)*40 + kq];
      bfv[i] = *(const bf16x8*)&sB[(wc + i*16 + lm)*40 + kq];
    }
    #pragma unroll
    for (int mi=0;mi<4;mi++)
      #pragma unroll
      for (int ni=0;ni<4;ni++)
        acc[mi][ni] = __builtin_amdgcn_mfma_f32_16x16x32_bf16(af[mi], bfv[ni], acc[mi][ni], 0,0,0);
  }
  int lr4 = (l>>4)<<2;
  #pragma unroll
  for (int mi=0;mi<4;mi++){
    int row0 = m0 + wr + mi*16 + lr4;
    #pragma unroll
    for (int ni=0;ni<4;ni++){
      int col = n0 + wc + ni*16 + lm;
      float bi = bias[col];
      #pragma unroll
      for (int r=0;r<4;r++){
        float v = acc[mi][ni][r] + bi;
        int row = row0 + r;
        if (EPI==1){
          v += res[(size_t)row*ldres + col];
          ((float*)Cp)[(size_t)row*ldc + col] = v;
        } else if (EPI==2){
          v = 0.5f*v*(1.f + erff(v*0.70710678118f));
          ((unsigned short*)Cp)[(size_t)row*ldc + col] = f2bf(v);
        } else {
          ((unsigned short*)Cp)[(size_t)row*ldc + col] = f2bf(v);
        }
      }
    }
  }
}

// ---------------- flash attention: per block one (b,h), 64 q rows ----------------
// 8 waves: qw = w>>2 (2 x 32 rows), dw = w&3 (4 x 128 d-cols).
// dw==0 waves own QK^T + online softmax; P + rescale factors go through LDS.
__global__ __launch_bounds__(512) void k_attn(const unsigned short* __restrict__ qkv,
                                              const unsigned short* __restrict__ Vt,
                                              unsigned short* __restrict__ out){
  __shared__ unsigned short sK[64*72];     // [keyrow][64 k, pad 72]
  __shared__ unsigned short sV[512*72];    // [d][64 keys, pad 72]
  __shared__ unsigned short sP[64*72];     // [qrow 0..63][64 keys, pad 72]
  __shared__ float sFac[2][32];
  int j = blockIdx.x;
  // XCD swizzle: all 32 q-blocks of one (b,h) land on one XCD -> V stays L2-resident
  int xcd = j&7, s_ = j>>3;
  int bh = xcd + ((s_>>5)<<3);
  int qb = s_&31;
  int b = bh>>3, h = bh&7;
  int t = threadIdx.x, l = t&63, w = t>>6;
  int qw = w>>2, dw = w&3;
  int q0 = qb<<6;
  int lm = l&15, kq = (l>>4)<<3, lr4 = (l>>4)<<2;
  const float scale = 0.125f;

  bf16x8 qf[2][2];
  #pragma unroll
  for (int mi=0;mi<2;mi++)
    #pragma unroll
    for (int kk=0;kk<2;kk++){
      int row = b*NN + q0 + qw*32 + mi*16 + lm;
      int col = h*HEAD_C + kk*32 + kq;
      qf[mi][kk] = *(const bf16x8*)(qkv + (size_t)row*QKV_DIM + col);
    }

  f32x4 o[2][8] = {};
  float m_[2][4], l_[2][4];
  #pragma unroll
  for (int mi=0;mi<2;mi++)
    #pragma unroll
    for (int r=0;r<4;r++){ m_[mi][r] = -1e30f; l_[mi][r] = 0.f; }

  int trow = t>>3, tc = (t&7)<<3;
  const unsigned short* pK = qkv + (size_t)(b*NN + trow)*QKV_DIM + IN_C + h*HEAD_C + tc;
  const unsigned short* pV = Vt + ((size_t)bh*IN_C + trow)*NN + tc;
  int vsoff = trow*72 + tc;

  for (int k0=0; k0<NN; k0+=64){
    bf16x8 kv = *(const bf16x8*)(pK + (size_t)k0*QKV_DIM);
    bf16x8 vv[8];
    #pragma unroll
    for (int c=0;c<8;c++)
      vv[c] = *(const bf16x8*)(pV + (size_t)(c*64)*NN + k0);
    __syncthreads();                      // prev iteration's LDS reads complete
    *(bf16x8*)&sK[vsoff] = kv;
    #pragma unroll
    for (int c=0;c<8;c++)
      *(bf16x8*)&sV[vsoff + c*64*72] = vv[c];
    __syncthreads();                      // tiles staged

    if (dw==0){
      f32x4 sacc[2][4] = {};
      #pragma unroll
      for (int kk=0;kk<2;kk++)
        #pragma unroll
        for (int ci=0;ci<4;ci++){
          bf16x8 kf = *(const bf16x8*)&sK[(ci*16 + lm)*72 + kk*32 + kq];
          #pragma unroll
          for (int mi=0;mi<2;mi++)
            sacc[mi][ci] = __builtin_amdgcn_mfma_f32_16x16x32_bf16(qf[mi][kk], kf, sacc[mi][ci], 0,0,0);
        }
      #pragma unroll
      for (int mi=0;mi<2;mi++){
        float mx[4];
        #pragma unroll
        for (int r=0;r<4;r++){
          float a0=sacc[mi][0][r]*scale, a1=sacc[mi][1][r]*scale,
                a2=sacc[mi][2][r]*scale, a3=sacc[mi][3][r]*scale;
          sacc[mi][0][r]=a0; sacc[mi][1][r]=a1; sacc[mi][2][r]=a2; sacc[mi][3][r]=a3;
          mx[r] = fmaxf(fmaxf(a0,a1), fmaxf(a2,a3));
        }
        #pragma unroll
        for (int d=1; d<16; d<<=1)
          #pragma unroll
          for (int r=0;r<4;r++) mx[r] = fmaxf(mx[r], __shfl_xor(mx[r], d));
        #pragma unroll
        for (int r=0;r<4;r++){
          float mn = fmaxf(m_[mi][r], mx[r]);
          float f = __expf(m_[mi][r] - mn);
          m_[mi][r] = mn;
          float p0 = __expf(sacc[mi][0][r]-mn), p1 = __expf(sacc[mi][1][r]-mn);
          float p2 = __expf(sacc[mi][2][r]-mn), p3 = __expf(sacc[mi][3][r]-mn);
          int prow = (qw*32 + mi*16 + lr4 + r)*72;
          sP[prow +  0 + lm] = f2bf(p0);
          sP[prow + 16 + lm] = f2bf(p1);
          sP[prow + 32 + lm] = f2bf(p2);
          sP[prow + 48 + lm] = f2bf(p3);
          float rsv = p0+p1+p2+p3;
          #pragma unroll
          for (int d=1; d<16; d<<=1) rsv += __shfl_xor(rsv, d);
          l_[mi][r] = l_[mi][r]*f + rsv;
          if (lm==0) sFac[qw][mi*16 + lr4 + r] = f;
        }
      }
    }
    __syncthreads();                      // P + factors ready

    float fc[2][4];
    #pragma unroll
    for (int mi=0;mi<2;mi++)
      #pragma unroll
      for (int r=0;r<4;r++)
        fc[mi][r] = sFac[qw][mi*16 + lr4 + r];
    #pragma unroll
    for (int mi=0;mi<2;mi++)
      #pragma unroll
      for (int di=0;di<8;di++)
        #pragma unroll
        for (int r=0;r<4;r++)
          o[mi][di][r] *= fc[mi][r];
    #pragma unroll
    for (int kk=0;kk<2;kk++){
      bf16x8 pf[2];
      #pragma unroll
      for (int mi=0;mi<2;mi++)
        pf[mi] = *(const bf16x8*)&sP[(qw*32 + mi*16 + lm)*72 + kk*32 + kq];
      #pragma unroll
      for (int di=0;di<8;di++){
        bf16x8 vf = *(const bf16x8*)&sV[(dw*128 + di*16 + lm)*72 + kk*32 + kq];
        #pragma unroll
        for (int mi=0;mi<2;mi++)
          o[mi][di] = __builtin_amdgcn_mfma_f32_16x16x32_bf16(pf[mi], vf, o[mi][di], 0,0,0);
      }
    }
  }

  __syncthreads();                        // last fc reads done before sFac reuse
  if (dw==0 && lm==0){
    #pragma unroll
    for (int mi=0;mi<2;mi++)
      #pragma unroll
      for (int r=0;r<4;r++)
        sFac[qw][mi*16 + lr4 + r] = l_[mi][r];
  }
  __syncthreads();
  #pragma unroll
  for (int mi=0;mi<2;mi++)
    #pragma unroll
    for (int r=0;r<4;r++){
      float inv = 1.f / sFac[qw][mi*16 + lr4 + r];
      int row = b*NN + q0 + qw*32 + mi*16 + lr4 + r;
      #pragma unroll
      for (int di=0;di<8;di++)
        out[(size_t)row*MERGE_K + h*IN_C + dw*128 + di*16 + lm] = f2bf(o[mi][di][r]*inv);
    }
}

extern "C" void kernel_launch(void* const* d_in, const int* in_sizes, int n_in,
                              void* d_out, int out_size, void* d_ws, size_t ws_size,
                              hipStream_t stream){
  const float* x       = (const float*)d_in[0];
  const float* tin     = (const float*)d_in[1];
  const float* ln1_g   = (const float*)d_in[2];
  const float* ln1_b   = (const float*)d_in[3];
  const float* qkv_w   = (const float*)d_in[4];
  const float* qkv_b   = (const float*)d_in[5];
  const float* merge_w = (const float*)d_in[6];
  const float* merge_b = (const float*)d_in[7];
  const float* time_w  = (const float*)d_in[8];
  const float* time_b  = (const float*)d_in[9];
  const float* ln2_g   = (const float*)d_in[10];
  const float* ln2_b   = (const float*)d_in[11];
  const float* ff1_w   = (const float*)d_in[12];
  const float* ff1_b   = (const float*)d_in[13];
  const float* ff2_w   = (const float*)d_in[14];
  const float* ff2_b   = (const float*)d_in[15];

  char* ws = (char*)d_ws;
  size_t off = 0;
  auto alloc = [&](size_t bytes)->void*{ void* p = ws + off; off += (bytes + 255) & ~(size_t)255; return p; };
  unsigned short* wqkvT   = (unsigned short*)alloc((size_t)QKV_DIM*IN_C*2);
  unsigned short* wmergeT = (unsigned short*)alloc((size_t)IN_C*MERGE_K*2);
  unsigned short* wff1T   = (unsigned short*)alloc((size_t)EXPAND_C*LN2_C*2);
  unsigned short* wff2T   = (unsigned short*)alloc((size_t)IN_C*EXPAND_C*2);
  float*          ttb     = (float*)alloc((size_t)NB*TIME_C*4);
  unsigned short* ln1o    = (unsigned short*)alloc((size_t)ROWS*IN_C*2);
  unsigned short* qkvb    = (unsigned short*)alloc((size_t)ROWS*QKV_DIM*2);
  unsigned short* vt      = (unsigned short*)alloc((size_t)NB*NHEAD*IN_C*NN*2);
  unsigned short* atto    = (unsigned short*)alloc((size_t)ROWS*MERGE_K*2);
  float*          x2      = (float*)alloc((size_t)ROWS*IN_C*4);
  // aliases over dead buffers (lifetimes verified):
  unsigned short* ln2o = vt;    // vt dead after k_attn
  unsigned short* hbuf = qkvb;  // qkvb dead after k_attn

  k_transpose_w<<<dim3(QKV_DIM/64, IN_C/64),  256, 0, stream>>>(qkv_w,   wqkvT,   IN_C,     QKV_DIM);
  k_transpose_w<<<dim3(IN_C/64,   MERGE_K/64),256, 0, stream>>>(merge_w, wmergeT, MERGE_K,  IN_C);
  k_transpose_w<<<dim3(EXPAND_C/64, LN2_C/64),256, 0, stream>>>(ff1_w,   wff1T,   LN2_C,    EXPAND_C);
  k_transpose_w<<<dim3(IN_C/64,   EXPAND_C/64),256, 0, stream>>>(ff2_w,  wff2T,   EXPAND_C, IN_C);
  k_time<<<dim3(NB), 256, 0, stream>>>(tin, time_w, time_b, ttb);
  k_ln1<<<dim3(ROWS/4), 256, 0, stream>>>(x, ln1_g, ln1_b, ln1o);

  k_gemm<0><<<dim3(QKV_DIM/128, ROWS/128), 256, 0, stream>>>(ln1o, IN_C, wqkvT, IN_C, qkv_b, nullptr, 0, qkvb, QKV_DIM, IN_C);
  k_transpose_v<<<dim3(8192), 256, 0, stream>>>(qkvb, vt);
  k_attn<<<dim3(1024), 512, 0, stream>>>(qkvb, vt, atto);
  k_gemm<1><<<dim3(IN_C/128, ROWS/128), 256, 0, stream>>>(atto, MERGE_K, wmergeT, MERGE_K, merge_b, x, IN_C, x2, IN_C, MERGE_K);
  k_ln2<<<dim3(ROWS/4), 256, 0, stream>>>(x2, ttb, ln2_g, ln2_b, ln2o);
  k_gemm<2><<<dim3(EXPAND_C/128, ROWS/128), 256, 0, stream>>>(ln2o, LN2_C, wff1T, LN2_C, ff1_b, nullptr, 0, hbuf, EXPAND_C, LN2_C);
  k_gemm<1><<<dim3(IN_C/128, ROWS/128), 256, 0, stream>>>(hbuf, EXPAND_C, wff2T, EXPAND_C, ff2_b, x2, IN_C, (float*)d_out, IN_C, EXPAND_C);

  (void)in_sizes; (void)n_in; (void)out_size; (void)ws_size;
}

// Round 2
// 782.655 us; speedup vs baseline: 1.0759x; 1.0759x over previous
//
#include <hip/hip_runtime.h>

#define IN_C 512
#define HEAD_C 64
#define NHEAD 8
#define TIME_C 256
#define EXPAND_C 2048
#define NB 4
#define NN 2048
#define QKV_DIM 5120   /* 64*8*2 + 512*8 */
#define ROWS (NB*NN)   /* 8192 */
#define MERGE_K (NHEAD*IN_C) /* 4096 */
#define LN2_C (IN_C+TIME_C)  /* 768 */

typedef __bf16 bf16x8 __attribute__((ext_vector_type(8)));
typedef float f32x4 __attribute__((ext_vector_type(4)));

__device__ __forceinline__ unsigned short f2bf(float f){
  unsigned int u = __builtin_bit_cast(unsigned int, f);
  u += 0x7fffu + ((u >> 16) & 1u);
  return (unsigned short)(u >> 16);
}

// ---------------- weight cast + transpose: W[K][N] f32 -> Wt[N][K] bf16 ----------------
__global__ __launch_bounds__(256) void k_transpose_w(const float* __restrict__ W,
                                                     unsigned short* __restrict__ Wt,
                                                     int K, int N){
  __shared__ unsigned short tile[64*72];
  int t = threadIdx.x;
  int kb = blockIdx.y<<6, nb = blockIdx.x<<6;
  {
    int kr = t>>2, nc = (t&3)<<4;
    const float* src = W + (size_t)(kb+kr)*N + nb + nc;
    alignas(16) unsigned short tmp[16];
    #pragma unroll
    for (int j=0;j<16;j+=4){
      float4 v = *(const float4*)(src + j);
      tmp[j+0]=f2bf(v.x); tmp[j+1]=f2bf(v.y); tmp[j+2]=f2bf(v.z); tmp[j+3]=f2bf(v.w);
    }
    *(bf16x8*)&tile[kr*72 + nc]     = *(bf16x8*)&tmp[0];
    *(bf16x8*)&tile[kr*72 + nc + 8] = *(bf16x8*)&tmp[8];
  }
  __syncthreads();
  {
    int nr = t>>2, kc = (t&3)<<4;
    alignas(16) unsigned short ov[16];
    #pragma unroll
    for (int i=0;i<16;i++) ov[i] = tile[(kc+i)*72 + nr];
    unsigned short* dst = Wt + (size_t)(nb+nr)*K + kb + kc;
    *(bf16x8*)dst     = *(bf16x8*)&ov[0];
    *(bf16x8*)(dst+8) = *(bf16x8*)&ov[8];
  }
}

// ---------------- V transpose: qkv[.,1024+h*512+d] -> Vt[bh][d][n] bf16 ----------------
__global__ __launch_bounds__(256) void k_transpose_v(const unsigned short* __restrict__ qkv,
                                                     unsigned short* __restrict__ Vt){
  __shared__ unsigned short tile[64*72];
  int j = blockIdx.x;              // bh(32) x db(8) x nb(32)
  int nbk = j&31, db=(j>>5)&7, bh=j>>8;
  int b = bh>>3, h = bh&7;
  int t = threadIdx.x;
  {
    int nr = t>>2, dc = (t&3)<<4;
    const unsigned short* src = qkv + (size_t)(b*NN + nbk*64 + nr)*QKV_DIM + 2*IN_C + h*IN_C + db*64 + dc;
    *(bf16x8*)&tile[nr*72 + dc]     = *(const bf16x8*)src;
    *(bf16x8*)&tile[nr*72 + dc + 8] = *(const bf16x8*)(src+8);
  }
  __syncthreads();
  {
    int dr = t>>2, nc = (t&3)<<4;
    alignas(16) unsigned short ov[16];
    #pragma unroll
    for (int i=0;i<16;i++) ov[i] = tile[(nc+i)*72 + dr];
    unsigned short* dst = Vt + ((size_t)bh*IN_C + db*64 + dr)*NN + nbk*64 + nc;
    *(bf16x8*)dst     = *(bf16x8*)&ov[0];
    *(bf16x8*)(dst+8) = *(bf16x8*)&ov[8];
  }
}

// ---------------- LN1: x[8192][512] f32 -> bf16 ----------------
__global__ __launch_bounds__(256) void k_ln1(const float* __restrict__ x,
                                             const float* __restrict__ g,
                                             const float* __restrict__ bta,
                                             unsigned short* __restrict__ out){
  int row = (blockIdx.x<<2) + (threadIdx.x>>6);
  int l = threadIdx.x&63;
  const float* px = x + (size_t)row*IN_C + l*8;
  alignas(16) float v[8];
  *(float4*)&v[0] = *(const float4*)px;
  *(float4*)&v[4] = *(const float4*)(px+4);
  float s=0.f, sq=0.f;
  #pragma unroll
  for (int j=0;j<8;j++){ s+=v[j]; sq+=v[j]*v[j]; }
  #pragma unroll
  for (int d=32; d>0; d>>=1){ s += __shfl_xor(s,d); sq += __shfl_xor(sq,d); }
  float mu = s*(1.f/IN_C);
  float var = sq*(1.f/IN_C) - mu*mu;
  float rstd = rsqrtf(var + 1e-5f);
  alignas(16) unsigned short o[8];
  #pragma unroll
  for (int j=0;j<8;j++){
    int c = l*8+j;
    o[j] = f2bf((v[j]-mu)*rstd*g[c] + bta[c]);
  }
  *(bf16x8*)(out + (size_t)row*IN_C + l*8) = *(bf16x8*)o;
}

// ---------------- time MLP: tt[b][j] = t[b] @ W + b ----------------
__global__ __launch_bounds__(256) void k_time(const float* __restrict__ t,
                                              const float* __restrict__ W,
                                              const float* __restrict__ bias,
                                              float* __restrict__ tt){
  int b = blockIdx.x, j = threadIdx.x;
  float acc = bias[j];
  const float* tr = t + b*TIME_C;
  #pragma unroll 4
  for (int c=0;c<TIME_C;c++) acc = fmaf(tr[c], W[c*TIME_C + j], acc);
  tt[b*TIME_C + j] = acc;
}

// ---------------- LN2 over concat(x2[512], tt[256]) -> bf16[8192][768] ----------------
__global__ __launch_bounds__(256) void k_ln2(const float* __restrict__ x2,
                                             const float* __restrict__ tt,
                                             const float* __restrict__ g,
                                             const float* __restrict__ bta,
                                             unsigned short* __restrict__ out){
  int row = (blockIdx.x<<2) + (threadIdx.x>>6);
  int l = threadIdx.x&63;
  int bi = row>>11;
  float v[12];
  int c0 = l*12;
  #pragma unroll
  for (int j=0;j<12;j++){
    int c = c0+j;
    v[j] = (c < IN_C) ? x2[(size_t)row*IN_C + c] : tt[bi*TIME_C + c - IN_C];
  }
  float s=0.f, sq=0.f;
  #pragma unroll
  for (int j=0;j<12;j++){ s+=v[j]; sq+=v[j]*v[j]; }
  #pragma unroll
  for (int d=32; d>0; d>>=1){ s += __shfl_xor(s,d); sq += __shfl_xor(sq,d); }
  float mu = s*(1.f/LN2_C);
  float var = sq*(1.f/LN2_C) - mu*mu;
  float rstd = rsqrtf(var + 1e-5f);
  #pragma unroll
  for (int j=0;j<12;j++){
    int c = c0+j;
    out[(size_t)row*LN2_C + c] = f2bf((v[j]-mu)*rstd*g[c] + bta[c]);
  }
}

// ---------------- GEMM: C[M][N] = A[M][K](bf16) @ Bt[N][K]^T(bf16) + bias (+res) ----------------
// EPI: 0 = bf16 out; 1 = f32 out + residual; 2 = bf16 out + exact gelu
template<int EPI>
__global__ __launch_bounds__(256) void k_gemm(const unsigned short* __restrict__ A, int lda,
                                              const unsigned short* __restrict__ Bt, int ldb,
                                              const float* __restrict__ bias,
                                              const float* __restrict__ res, int ldres,
                                              void* __restrict__ Cp, int ldc, int K){
  __shared__ unsigned short sA[128*40];   // [128 rows][32 k, pad to 40]
  __shared__ unsigned short sB[128*40];
  int t = threadIdx.x;
  int l = t&63, w = t>>6;
  int m0 = blockIdx.y<<7, n0 = blockIdx.x<<7;
  int wr = (w>>1)<<6, wc = (w&1)<<6;
  int lm = l&15, kq = (l>>4)<<3;
  f32x4 acc[4][4] = {};
  int sr = t>>2, sc = (t&3)<<3;
  const unsigned short* pA = A + (size_t)(m0+sr)*lda + sc;
  const unsigned short* pB = Bt + (size_t)(n0+sr)*ldb + sc;
  int soff = sr*40 + sc;
  for (int k0=0; k0<K; k0+=32){
    bf16x8 a0 = *(const bf16x8*)pA;
    bf16x8 a1 = *(const bf16x8*)(pA + (size_t)64*lda);
    bf16x8 b0 = *(const bf16x8*)pB;
    bf16x8 b1 = *(const bf16x8*)(pB + (size_t)64*ldb);
    pA += 32; pB += 32;
    __syncthreads();
    *(bf16x8*)&sA[soff]         = a0;
    *(bf16x8*)&sA[soff + 64*40] = a1;
    *(bf16x8*)&sB[soff]         = b0;
    *(bf16x8*)&sB[soff + 64*40] = b1;
    __syncthreads();
    bf16x8 af[4], bfv[4];
    #pragma unroll
    for (int i=0;i<4;i++){
      af[i]  = *(const bf16x8*)&sA[(wr + i*16 + lm)*40 + kq];
      bfv[i] = *(const bf16x8*)&sB[(wc + i*16 + lm)*40 + kq];
    }
    #pragma unroll
    for (int mi=0;mi<4;mi++)
      #pragma unroll
      for (int ni=0;ni<4;ni++)
        acc[mi][ni] = __builtin_amdgcn_mfma_f32_16x16x32_bf16(af[mi], bfv[ni], acc[mi][ni], 0,0,0);
  }
  int lr4 = (l>>4)<<2;
  #pragma unroll
  for (int mi=0;mi<4;mi++){
    int row0 = m0 + wr + mi*16 + lr4;
    #pragma unroll
    for (int ni=0;ni<4;ni++){
      int col = n0 + wc + ni*16 + lm;
      float bi = bias[col];
      #pragma unroll
      for (int r=0;r<4;r++){
        float v = acc[mi][ni][r] + bi;
        int row = row0 + r;
        if (EPI==1){
          v += res[(size_t)row*ldres + col];
          ((float*)Cp)[(size_t)row*ldc + col] = v;
        } else if (EPI==2){
          v = 0.5f*v*(1.f + erff(v*0.70710678118f));
          ((unsigned short*)Cp)[(size_t)row*ldc + col] = f2bf(v);
        } else {
          ((unsigned short*)Cp)[(size_t)row*ldc + col] = f2bf(v);
        }
      }
    }
  }
}

// ---------------- flash attention v2: all-wave participation ----------------
// Block = one (b,h) x 64 q-rows. 8 waves, wave w owns d-slice [w*64, w*64+64).
// KVBLK=256: wave w computes QK^T for keys [k0+w*32, k0+w*32+32) -> all waves busy.
// Softmax: lane acts as row-owner for row==lane (running m,l replicated per wave in
// 2 regs); per-row partials combined via small LDS arrays; factors distributed to
// MFMA C-layout rows via __shfl. V fragments read directly from L2 (Vt, XCD-resident),
// no LDS staging. 2 barriers per 256 keys.
__global__ __launch_bounds__(512, 2) void k_attn(const unsigned short* __restrict__ qkv,
                                                 const unsigned short* __restrict__ Vt,
                                                 unsigned short* __restrict__ out){
  __shared__ unsigned short sP[64][264];   // P tile, pad->row stride 33*16B (b128 conflict-free)
  __shared__ float sMax[64][12];           // [row][wave partials], stride 48B (16B aligned)
  __shared__ float sSum[64][12];
  int j = blockIdx.x;
  // XCD swizzle: 32 q-blocks of one (b,h) land on one XCD -> V (2MB) + K L2-resident
  int xcd = j&7, s_ = j>>3;
  int bh = xcd + ((s_>>5)<<3);
  int qb = s_&31;
  int b = bh>>3, h = bh&7;
  int t = threadIdx.x, l = t&63, w = t>>6;
  int q0 = qb<<6;
  int lm = l&15, g = l>>4, kq = g<<3, lr4 = g<<2;
  const float scale = 0.125f;

  // Q fragments: rows q0..q0+63, all 64 head dims
  bf16x8 qf[4][2];
  #pragma unroll
  for (int mi=0;mi<4;mi++)
    #pragma unroll
    for (int kk=0;kk<2;kk++)
      qf[mi][kk] = *(const bf16x8*)(qkv + (size_t)(b*NN + q0 + mi*16 + lm)*QKV_DIM + h*HEAD_C + kk*32 + kq);

  f32x4 o[4][4] = {};
  float m_row = -3.0e38f, l_row = 0.f;   // running state for row == l (replicated per wave)

  const unsigned short* Kbase = qkv + (size_t)(b*NN)*QKV_DIM + IN_C + h*HEAD_C;
  const unsigned short* Vbase = Vt + ((size_t)bh*IN_C + w*64)*NN;

  for (int k0=0; k0<NN; k0+=256){
    int kw0 = k0 + w*32;
    // ---- phase 1: S = Q @ K^T for this wave's 32 keys ----
    f32x4 sacc[4][2] = {};
    #pragma unroll
    for (int kk=0;kk<2;kk++)
      #pragma unroll
      for (int ni=0;ni<2;ni++){
        bf16x8 kf = *(const bf16x8*)(Kbase + (size_t)(kw0 + ni*16 + lm)*QKV_DIM + kk*32 + kq);
        #pragma unroll
        for (int mi=0;mi<4;mi++)
          sacc[mi][ni] = __builtin_amdgcn_mfma_f32_16x16x32_bf16(qf[mi][kk], kf, sacc[mi][ni], 0,0,0);
      }
    // per-row partial max over the wave's 32 keys
    float pm[4][4];
    #pragma unroll
    for (int mi=0;mi<4;mi++)
      #pragma unroll
      for (int r=0;r<4;r++)
        pm[mi][r] = fmaxf(sacc[mi][0][r], sacc[mi][1][r]);
    #pragma unroll
    for (int d=1; d<16; d<<=1)
      #pragma unroll
      for (int mi=0;mi<4;mi++)
        #pragma unroll
        for (int r=0;r<4;r++)
          pm[mi][r] = fmaxf(pm[mi][r], __shfl_xor(pm[mi][r], d));
    if (lm==0){
      #pragma unroll
      for (int mi=0;mi<4;mi++)
        #pragma unroll
        for (int r=0;r<4;r++)
          sMax[mi*16+lr4+r][w] = pm[mi][r];
    }
    __syncthreads();   // B1: sMax ready; prev iter's sP reads complete

    // ---- phase 2: row-owner combine (row == l), distribute, P, partial sums ----
    float4 x0 = *(const float4*)&sMax[l][0];
    float4 x1 = *(const float4*)&sMax[l][4];
    float mx = fmaxf(fmaxf(fmaxf(x0.x,x0.y),fmaxf(x0.z,x0.w)),
                     fmaxf(fmaxf(x1.x,x1.y),fmaxf(x1.z,x1.w))) * scale;
    float mn = fmaxf(m_row, mx);
    float fl = __expf(m_row - mn);
    m_row = mn;
    float mnv[4][4], fv[4][4];
    #pragma unroll
    for (int mi=0;mi<4;mi++)
      #pragma unroll
      for (int r=0;r<4;r++){
        mnv[mi][r] = __shfl(mn, mi*16+lr4+r);
        fv[mi][r]  = __shfl(fl, mi*16+lr4+r);
      }
    #pragma unroll
    for (int mi=0;mi<4;mi++)
      #pragma unroll
      for (int ni=0;ni<4;ni++)
        #pragma unroll
        for (int r=0;r<4;r++)
          o[mi][ni][r] *= fv[mi][r];
    float ps[4][4];
    #pragma unroll
    for (int mi=0;mi<4;mi++)
      #pragma unroll
      for (int r=0;r<4;r++){
        float p0 = __expf(fmaf(sacc[mi][0][r], scale, -mnv[mi][r]));
        float p1 = __expf(fmaf(sacc[mi][1][r], scale, -mnv[mi][r]));
        int row = mi*16+lr4+r;
        sP[row][w*32 + lm]      = f2bf(p0);
        sP[row][w*32 + 16 + lm] = f2bf(p1);
        ps[mi][r] = p0 + p1;
      }
    #pragma unroll
    for (int d=1; d<16; d<<=1)
      #pragma unroll
      for (int mi=0;mi<4;mi++)
        #pragma unroll
        for (int r=0;r<4;r++)
          ps[mi][r] += __shfl_xor(ps[mi][r], d);
    if (lm==0){
      #pragma unroll
      for (int mi=0;mi<4;mi++)
        #pragma unroll
        for (int r=0;r<4;r++)
          sSum[mi*16+lr4+r][w] = ps[mi][r];
    }
    __syncthreads();   // B2: sP + sSum ready

    float4 s0 = *(const float4*)&sSum[l][0];
    float4 s1 = *(const float4*)&sSum[l][4];
    float ts = (s0.x+s0.y)+(s0.z+s0.w) + (s1.x+s1.y)+(s1.z+s1.w);
    l_row = l_row * fl + ts;

    // ---- phase 3: PV, V fragments straight from L2 ----
    #pragma unroll
    for (int kk=0;kk<8;kk++){
      bf16x8 pf[4];
      #pragma unroll
      for (int mi=0;mi<4;mi++)
        pf[mi] = *(const bf16x8*)&sP[mi*16+lm][kk*32+kq];
      #pragma unroll
      for (int ni=0;ni<4;ni++){
        bf16x8 vf = *(const bf16x8*)(Vbase + (size_t)(ni*16+lm)*NN + k0 + kk*32 + kq);
        #pragma unroll
        for (int mi=0;mi<4;mi++)
          o[mi][ni] = __builtin_amdgcn_mfma_f32_16x16x32_bf16(pf[mi], vf, o[mi][ni], 0,0,0);
      }
    }
  }

  float inv = 1.f / l_row;
  float iv[4][4];
  #pragma unroll
  for (int mi=0;mi<4;mi++)
    #pragma unroll
    for (int r=0;r<4;r++)
      iv[mi][r] = __shfl(inv, mi*16+lr4+r);
  #pragma unroll
  for (int mi=0;mi<4;mi++)
    #pragma unroll
    for (int r=0;r<4;r++){
      size_t grow = (size_t)(b*NN + q0 + mi*16 + lr4 + r);
      #pragma unroll
      for (int ni=0;ni<4;ni++)
        out[grow*MERGE_K + h*IN_C + w*64 + ni*16 + lm] = f2bf(o[mi][ni][r]*iv[mi][r]);
    }
}

extern "C" void kernel_launch(void* const* d_in, const int* in_sizes, int n_in,
                              void* d_out, int out_size, void* d_ws, size_t ws_size,
                              hipStream_t stream){
  const float* x       = (const float*)d_in[0];
  const float* tin     = (const float*)d_in[1];
  const float* ln1_g   = (const float*)d_in[2];
  const float* ln1_b   = (const float*)d_in[3];
  const float* qkv_w   = (const float*)d_in[4];
  const float* qkv_b   = (const float*)d_in[5];
  const float* merge_w = (const float*)d_in[6];
  const float* merge_b = (const float*)d_in[7];
  const float* time_w  = (const float*)d_in[8];
  const float* time_b  = (const float*)d_in[9];
  const float* ln2_g   = (const float*)d_in[10];
  const float* ln2_b   = (const float*)d_in[11];
  const float* ff1_w   = (const float*)d_in[12];
  const float* ff1_b   = (const float*)d_in[13];
  const float* ff2_w   = (const float*)d_in[14];
  const float* ff2_b   = (const float*)d_in[15];

  char* ws = (char*)d_ws;
  size_t off = 0;
  auto alloc = [&](size_t bytes)->void*{ void* p = ws + off; off += (bytes + 255) & ~(size_t)255; return p; };
  unsigned short* wqkvT   = (unsigned short*)alloc((size_t)QKV_DIM*IN_C*2);
  unsigned short* wmergeT = (unsigned short*)alloc((size_t)IN_C*MERGE_K*2);
  unsigned short* wff1T   = (unsigned short*)alloc((size_t)EXPAND_C*LN2_C*2);
  unsigned short* wff2T   = (unsigned short*)alloc((size_t)IN_C*EXPAND_C*2);
  float*          ttb     = (float*)alloc((size_t)NB*TIME_C*4);
  unsigned short* ln1o    = (unsigned short*)alloc((size_t)ROWS*IN_C*2);
  unsigned short* qkvb    = (unsigned short*)alloc((size_t)ROWS*QKV_DIM*2);
  unsigned short* vt      = (unsigned short*)alloc((size_t)NB*NHEAD*IN_C*NN*2);
  unsigned short* atto    = (unsigned short*)alloc((size_t)ROWS*MERGE_K*2);
  float*          x2      = (float*)alloc((size_t)ROWS*IN_C*4);
  // aliases over dead buffers (lifetimes verified):
  unsigned short* ln2o = vt;    // vt dead after k_attn
  unsigned short* hbuf = qkvb;  // qkvb dead after k_attn

  k_transpose_w<<<dim3(QKV_DIM/64, IN_C/64),  256, 0, stream>>>(qkv_w,   wqkvT,   IN_C,     QKV_DIM);
  k_transpose_w<<<dim3(IN_C/64,   MERGE_K/64),256, 0, stream>>>(merge_w, wmergeT, MERGE_K,  IN_C);
  k_transpose_w<<<dim3(EXPAND_C/64, LN2_C/64),256, 0, stream>>>(ff1_w,   wff1T,   LN2_C,    EXPAND_C);
  k_transpose_w<<<dim3(IN_C/64,   EXPAND_C/64),256, 0, stream>>>(ff2_w,  wff2T,   EXPAND_C, IN_C);
  k_time<<<dim3(NB), 256, 0, stream>>>(tin, time_w, time_b, ttb);
  k_ln1<<<dim3(ROWS/4), 256, 0, stream>>>(x, ln1_g, ln1_b, ln1o);

  k_gemm<0><<<dim3(QKV_DIM/128, ROWS/128), 256, 0, stream>>>(ln1o, IN_C, wqkvT, IN_C, qkv_b, nullptr, 0, qkvb, QKV_DIM, IN_C);
  k_transpose_v<<<dim3(8192), 256, 0, stream>>>(qkvb, vt);
  k_attn<<<dim3(1024), 512, 0, stream>>>(qkvb, vt, atto);
  k_gemm<1><<<dim3(IN_C/128, ROWS/128), 256, 0, stream>>>(atto, MERGE_K, wmergeT, MERGE_K, merge_b, x, IN_C, x2, IN_C, MERGE_K);
  k_ln2<<<dim3(ROWS/4), 256, 0, stream>>>(x2, ttb, ln2_g, ln2_b, ln2o);
  k_gemm<2><<<dim3(EXPAND_C/128, ROWS/128), 256, 0, stream>>>(ln2o, LN2_C, wff1T, LN2_C, ff1_b, nullptr, 0, hbuf, EXPAND_C, LN2_C);
  k_gemm<1><<<dim3(IN_C/128, ROWS/128), 256, 0, stream>>>(hbuf, EXPAND_C, wff2T, EXPAND_C, ff2_b, x2, IN_C, (float*)d_out, IN_C, EXPAND_C);

  (void)in_sizes; (void)n_in; (void)out_size; (void)ws_size;
}